// Round 4
// baseline (514.674 us; speedup 1.0000x reference)
//
#include <hip/hip_runtime.h>
#include <stdint.h>

#define NCLS 19
#define HW   (768 * 768)          // 589824
#define NPIX (8 * HW)             // 4718592
#define NGRP (NPIX / 4)           // 1179648 groups of 4 pixels
#define MINKEPT 131072u
#define NBINS 8192
#define BLOCK 256
#define GRID_MAIN (NPIX / 1024)   // 4608 psum entries (layout/order preserved)

// k_main geometry: class-outer sweep, big contiguous chunks, few DRAM streams
#define U     9                   // f4 groups per thread per class
#define PXB   (U * BLOCK * 4)     // 9216 pixels per block
#define GRID_K1 (NPIX / PXB)      // 512 blocks = exactly 2 per CU
#define BPI   (HW / PXB)          // 64 blocks per image (exact)

// workspace layout (bytes) — all write-before-read, no memset required
#define OFF_PSUM  ((size_t)0)                          // GRID_MAIN f32 partial sums
#define OFF_PCS   ((size_t)GRID_MAIN * 4)              // GRID_MAIN u32 sel-cnt
#define OFF_PCV   ((size_t)GRID_MAIN * 8)              // GRID_MAIN u32 valid-cnt
#define OFF_PROB  ((size_t)GRID_MAIN * 12)             // NPIX u32  (fallback only)
#define OFF_LOSS  (OFF_PROB + (size_t)NPIX * 4)        // NPIX f32  (fallback only)

typedef float    f4 __attribute__((ext_vector_type(4)));
typedef int      i4 __attribute__((ext_vector_type(4)));
typedef unsigned u4 __attribute__((ext_vector_type(4)));

struct Grp { u4 pb; f4 lo; float ls; unsigned sc; unsigned vc; };

// Pure per-group function (4 px) — used by the exact fallback only; per-pixel
// math is bit-identical to k_main's class-outer loop (same c-order adds).
__device__ __forceinline__ Grp compute4(const float* __restrict__ predict,
                                        const int* __restrict__ target,
                                        const float* __restrict__ wsh, int g)
{
    int n = g / HW;
    int p = g - n * HW;
    const float* base = predict + (size_t)n * ((size_t)NCLS * HW) + p;

    i4 t4 = __builtin_nontemporal_load((const i4*)(target + g));
    int tcx = (t4.x == -1) ? 0 : t4.x;
    int tcy = (t4.y == -1) ? 0 : t4.y;
    int tcz = (t4.z == -1) ? 0 : t4.z;
    int tcw = (t4.w == -1) ? 0 : t4.w;

    f4 s  = {0.f, 0.f, 0.f, 0.f};
    f4 vt = {0.f, 0.f, 0.f, 0.f};
#pragma unroll
    for (int c = 0; c < NCLS; ++c) {
        f4 v = __builtin_nontemporal_load((const f4*)(base + (size_t)c * HW));
        s.x += __expf(v.x); s.y += __expf(v.y);
        s.z += __expf(v.z); s.w += __expf(v.w);
        vt.x = (c == tcx) ? v.x : vt.x;
        vt.y = (c == tcy) ? v.y : vt.y;
        vt.z = (c == tcz) ? v.z : vt.z;
        vt.w = (c == tcw) ? v.w : vt.w;
    }

    bool vx = (t4.x != -1), vy = (t4.y != -1), vz = (t4.z != -1), vw = (t4.w != -1);
    float lpx = vt.x - __logf(s.x), lpy = vt.y - __logf(s.y);
    float lpz = vt.z - __logf(s.z), lpw = vt.w - __logf(s.w);
    float px = __expf(lpx), py = __expf(lpy), pz = __expf(lpz), pw = __expf(lpw);

    Grp r;
    r.pb.x = vx ? __float_as_uint(px) : 0x7F800000u;
    r.pb.y = vy ? __float_as_uint(py) : 0x7F800000u;
    r.pb.z = vz ? __float_as_uint(pz) : 0x7F800000u;
    r.pb.w = vw ? __float_as_uint(pw) : 0x7F800000u;
    r.lo.x = vx ? (-wsh[tcx] * lpx) : 0.f;
    r.lo.y = vy ? (-wsh[tcy] * lpy) : 0.f;
    r.lo.z = vz ? (-wsh[tcz] * lpz) : 0.f;
    r.lo.w = vw ? (-wsh[tcw] * lpw) : 0.f;
    bool sx = vx && (px < 0.9f), sy = vy && (py < 0.9f);
    bool sz = vz && (pz < 0.9f), sw = vw && (pw < 0.9f);
    r.ls = (sx ? r.lo.x : 0.f) + (sy ? r.lo.y : 0.f) +
           (sz ? r.lo.z : 0.f) + (sw ? r.lo.w : 0.f);
    r.sc = (unsigned)sx + (unsigned)sy + (unsigned)sz + (unsigned)sw;
    r.vc = (unsigned)vx + (unsigned)vy + (unsigned)vz + (unsigned)vw;
    return r;
}

// ---------------------------------------------------------------------------
// K1: streaming pass, class-outer. Each block owns 9216 contiguous pixels;
// per class it reads ONE 36KB contiguous chunk (9 f4/thread). Chip-wide this
// presents ~512 large sequential streams to the DRAM controllers instead of
// ~39K interleaved 4KB streams (R2 form measured ~1.8 TB/s = 28% of the
// 6.6 TB/s the poison fill achieves in the same window; theory: row-miss
// dominated). Accumulators live in registers (s[9], vt[9]); targets packed
// one byte/pixel (0x80 = ignore) in 9 u32.
// psum layout/tree identical to the 4608-block original: psum[bid*9+u] is
// the 1024-px segment starting at pixel 9216*bid + 1024*u, reduced by the
// same 256-thread shuffle tree with the same lane mapping -> bit-identical.
__global__ __launch_bounds__(BLOCK, 2) void k_main(
    const float* __restrict__ predict, const int* __restrict__ target,
    const float* __restrict__ weight, float* __restrict__ psum,
    unsigned* __restrict__ pcs, unsigned* __restrict__ pcv)
{
    __shared__ float wsh[32];
    __shared__ float red_f[4];
    __shared__ unsigned red_a[4], red_b[4];
    int tid = threadIdx.x, bid = blockIdx.x;
    if (tid < NCLS) wsh[tid] = weight[tid];
    __syncthreads();

    int n  = bid / BPI;                    // image index (64 blocks/image)
    int p0 = (bid - n * BPI) * PXB;        // pixel offset within image
    const float* base = predict + (size_t)n * ((size_t)NCLS * HW) + p0;
    const int*   tb   = target  + (size_t)n * HW + p0;

    // targets: one byte per pixel, 0x80 sentinel for ignore
    unsigned tpk[U];
#pragma unroll
    for (int u = 0; u < U; ++u) {
        i4 t4 = __builtin_nontemporal_load((const i4*)(tb + u * 1024 + tid * 4));
        unsigned b0 = (t4.x == -1) ? 0x80u : (unsigned)t4.x;
        unsigned b1 = (t4.y == -1) ? 0x80u : (unsigned)t4.y;
        unsigned b2 = (t4.z == -1) ? 0x80u : (unsigned)t4.z;
        unsigned b3 = (t4.w == -1) ? 0x80u : (unsigned)t4.w;
        tpk[u] = b0 | (b1 << 8) | (b2 << 16) | (b3 << 24);
    }

    f4 s[U], vt[U];
#pragma unroll
    for (int u = 0; u < U; ++u) {
        s[u]  = (f4){0.f, 0.f, 0.f, 0.f};
        vt[u] = (f4){0.f, 0.f, 0.f, 0.f};
    }

#pragma unroll
    for (int c = 0; c < NCLS; ++c) {
        f4 v[U];
#pragma unroll
        for (int u = 0; u < U; ++u)
            v[u] = __builtin_nontemporal_load(
                (const f4*)(base + (size_t)c * HW + u * 1024 + tid * 4));
#pragma unroll
        for (int u = 0; u < U; ++u) {
            s[u].x += __expf(v[u].x); s[u].y += __expf(v[u].y);
            s[u].z += __expf(v[u].z); s[u].w += __expf(v[u].w);
            int b0 = (int)(tpk[u] & 0xFFu);
            int b1 = (int)((tpk[u] >> 8) & 0xFFu);
            int b2 = (int)((tpk[u] >> 16) & 0xFFu);
            int b3 = (int)(tpk[u] >> 24);
            vt[u].x = (c == b0) ? v[u].x : vt[u].x;
            vt[u].y = (c == b1) ? v[u].y : vt[u].y;
            vt[u].z = (c == b2) ? v[u].z : vt[u].z;
            vt[u].w = (c == b3) ? v[u].w : vt[u].w;
        }
    }

    // finalize + 9 reduction trees (identical math/order to original blocks)
#pragma unroll 1
    for (int u = 0; u < U; ++u) {
        int b0 = (int)(tpk[u] & 0xFFu);
        int b1 = (int)((tpk[u] >> 8) & 0xFFu);
        int b2 = (int)((tpk[u] >> 16) & 0xFFu);
        int b3 = (int)(tpk[u] >> 24);
        bool vx = b0 != 0x80, vy = b1 != 0x80, vz = b2 != 0x80, vw = b3 != 0x80;
        float lpx = vt[u].x - __logf(s[u].x), lpy = vt[u].y - __logf(s[u].y);
        float lpz = vt[u].z - __logf(s[u].z), lpw = vt[u].w - __logf(s[u].w);
        float px = __expf(lpx), py = __expf(lpy);
        float pz = __expf(lpz), pw = __expf(lpw);
        float lox  = vx ? (-wsh[b0 & 0x1F] * lpx) : 0.f;
        float loy  = vy ? (-wsh[b1 & 0x1F] * lpy) : 0.f;
        float loz  = vz ? (-wsh[b2 & 0x1F] * lpz) : 0.f;
        float low_ = vw ? (-wsh[b3 & 0x1F] * lpw) : 0.f;
        bool sx = vx && (px < 0.9f), sy = vy && (py < 0.9f);
        bool sz = vz && (pz < 0.9f), sw = vw && (pw < 0.9f);
        float lsum = (sx ? lox : 0.f) + (sy ? loy : 0.f) +
                     (sz ? loz : 0.f) + (sw ? low_ : 0.f);
        unsigned scnt = (unsigned)sx + (unsigned)sy + (unsigned)sz + (unsigned)sw;
        unsigned vcnt = (unsigned)vx + (unsigned)vy + (unsigned)vz + (unsigned)vw;

#pragma unroll
        for (int d = 32; d > 0; d >>= 1) {
            lsum += __shfl_down(lsum, d);
            scnt += __shfl_down(scnt, d);
            vcnt += __shfl_down(vcnt, d);
        }
        if ((tid & 63) == 0) { red_f[tid >> 6] = lsum; red_a[tid >> 6] = scnt; red_b[tid >> 6] = vcnt; }
        __syncthreads();
        if (tid == 0) {
            psum[bid * U + u] = red_f[0] + red_f[1] + red_f[2] + red_f[3];
            pcs[bid * U + u]  = red_a[0] + red_a[1] + red_a[2] + red_a[3];
            pcv[bid * U + u]  = red_b[0] + red_b[1] + red_b[2] + red_b[3];
        }
        __syncthreads();
    }
}

// ---------------------------------------------------------------------------
// K2: reduce partials; decide path; write output on the common path.
// Rare path (k-th order stat >= 0.9): this SINGLE block performs the entire
// exact OHEM computation sequentially (materialize, 3-level radix select in
// LDS, select-reduce). Slow (ms) but never taken on the common path.
__global__ __launch_bounds__(BLOCK) void k_decide_fb(
    const float* __restrict__ predict, const int* __restrict__ target,
    const float* __restrict__ weight,
    const float* __restrict__ psum, const unsigned* __restrict__ pcs,
    const unsigned* __restrict__ pcv,
    unsigned* __restrict__ probbits, float* __restrict__ lossbuf,
    float* __restrict__ out)
{
    __shared__ double red_d[4];
    __shared__ unsigned red_a[4], red_b[4];
    __shared__ unsigned sh_common, sh_k;
    __shared__ float wsh[32];
    __shared__ unsigned h[NBINS];
    __shared__ unsigned wtot[4], wpre[4];
    __shared__ unsigned sel_bin, sel_rem;

    int tid = threadIdx.x;
    int lane = tid & 63, wid = tid >> 6;

    // ---- decide (common-path arithmetic identical to previous rounds) ----
    double ds = 0.0; unsigned cs = 0, cv = 0;
    for (int i = tid; i < GRID_MAIN; i += BLOCK) {
        ds += (double)psum[i]; cs += pcs[i]; cv += pcv[i];
    }
#pragma unroll
    for (int d = 32; d > 0; d >>= 1) {
        ds += __shfl_down(ds, d); cs += __shfl_down(cs, d); cv += __shfl_down(cv, d);
    }
    if (lane == 0) { red_d[wid] = ds; red_a[wid] = cs; red_b[wid] = cv; }
    __syncthreads();
    if (tid == 0) {
        double sum = red_d[0] + red_d[1] + red_d[2] + red_d[3];
        unsigned cb = red_a[0] + red_a[1] + red_a[2] + red_a[3];
        unsigned nv = red_b[0] + red_b[1] + red_b[2] + red_b[3];
        unsigned km = nv - 1u;
        unsigned k  = (MINKEPT < km) ? MINKEPT : km;
        bool common = cb > k;          // k-th order stat < 0.9 => threshold == 0.9
        sh_common = common ? 1u : 0u;
        sh_k = k;
        if (common) out[0] = (float)(sum / (double)cb);
    }
    __syncthreads();
    if (sh_common) return;             // block-uniform exit

    // =====================================================================
    // Exact fallback — single block, sequential phases.
    // =====================================================================
    unsigned k = sh_k;
    if (tid < NCLS) wsh[tid] = weight[tid];
    __syncthreads();

    // Phase A: materialize probbits + lossbuf (bit-identical recompute).
    for (int idx = tid; idx < NGRP; idx += BLOCK) {
        int g = idx * 4;
        Grp r = compute4(predict, target, wsh, g);
        *(u4*)(probbits + g) = r.pb;
        *(f4*)(lossbuf + g)  = r.lo;
    }
    __syncthreads();

    // Phase B: 3-level radix select for the exact k-th smallest prob bits.
    unsigned pref = 0, krem = k, tb = 0;
    for (int level = 0; level < 3; ++level) {
        for (int i = tid; i < NBINS; i += BLOCK) h[i] = 0;
        __syncthreads();
        for (int i = tid; i < NPIX; i += BLOCK) {
            unsigned pb = probbits[i];
            if (level == 0) atomicAdd(&h[pb >> 19], 1u);
            else if (level == 1) { if ((pb >> 19) == pref) atomicAdd(&h[(pb >> 6) & (NBINS - 1)], 1u); }
            else                 { if ((pb >> 6)  == pref) atomicAdd(&h[pb & 63u], 1u); }
        }
        __syncthreads();

        // scan of 8192 bins: 256 threads x 32 bins each
        unsigned vals[32];
        unsigned s = 0;
#pragma unroll
        for (int j = 0; j < 32; ++j) { vals[j] = h[tid * 32 + j]; s += vals[j]; }
        unsigned x = s;
        for (int d = 1; d < 64; d <<= 1) {
            unsigned y = __shfl_up(x, d);
            if (lane >= d) x += y;
        }
        if (lane == 63) wtot[wid] = x;
        __syncthreads();
        if (tid == 0) {
            unsigned a = 0;
            for (int i = 0; i < 4; ++i) { wpre[i] = a; a += wtot[i]; }
        }
        __syncthreads();
        unsigned excl = x + wpre[wid] - s;

        if (s > 0 && krem >= excl && krem < excl + s) {   // exactly one thread
            unsigned rem = krem - excl;
            unsigned cum = 0, kn = 0; int bsel = 0; bool found = false;
#pragma unroll
            for (int j = 0; j < 32; ++j) {
                if (!found && rem < cum + vals[j]) { bsel = j; kn = rem - cum; found = true; }
                cum += vals[j];
            }
            sel_bin = (unsigned)(tid * 32 + bsel);
            sel_rem = kn;
        }
        __syncthreads();
        if (level == 0)      { pref = sel_bin;                krem = sel_rem; }
        else if (level == 1) { pref = (pref << 13) | sel_bin; krem = sel_rem; }
        else                 { tb = (pref << 6) | sel_bin; }
        __syncthreads();   // protect h/sel_* before next level's reuse
    }

    // Phase C: threshold = max(kth order stat, 0.9); select-reduce; write.
    unsigned tbits = __float_as_uint(fmaxf(__uint_as_float(tb), 0.9f));
    double sacc = 0.0; unsigned c = 0;
    for (int i = tid; i < NPIX; i += BLOCK) {
        unsigned pb = probbits[i];
        if (pb < tbits) { sacc += (double)lossbuf[i]; c++; }   // uint cmp == float cmp for +floats
    }
#pragma unroll
    for (int d = 32; d > 0; d >>= 1) { sacc += __shfl_down(sacc, d); c += __shfl_down(c, d); }
    if (lane == 0) { red_d[wid] = sacc; red_a[wid] = c; }
    __syncthreads();
    if (tid == 0) {
        double dt = red_d[0] + red_d[1] + red_d[2] + red_d[3];
        unsigned cc = red_a[0] + red_a[1] + red_a[2] + red_a[3];
        out[0] = (float)(dt / (double)cc);
    }
}

// ---------------------------------------------------------------------------
extern "C" void kernel_launch(void* const* d_in, const int* in_sizes, int n_in,
                              void* d_out, int out_size, void* d_ws, size_t ws_size,
                              hipStream_t stream)
{
    const float* predict = (const float*)d_in[0];
    const int*   target  = (const int*)d_in[1];
    const float* weight  = (const float*)d_in[2];
    char* ws = (char*)d_ws;
    float* out = (float*)d_out;

    float*    psum     = (float*)(ws + OFF_PSUM);
    unsigned* pcs      = (unsigned*)(ws + OFF_PCS);
    unsigned* pcv      = (unsigned*)(ws + OFF_PCV);
    unsigned* probbits = (unsigned*)(ws + OFF_PROB);
    float*    lossbuf  = (float*)(ws + OFF_LOSS);

    k_main<<<GRID_K1, BLOCK, 0, stream>>>(predict, target, weight, psum, pcs, pcv);
    k_decide_fb<<<1, BLOCK, 0, stream>>>(predict, target, weight,
                                         psum, pcs, pcv, probbits, lossbuf, out);
}

// Round 5
// 454.353 us; speedup vs baseline: 1.1328x; 1.1328x over previous
//
#include <hip/hip_runtime.h>
#include <stdint.h>

#define NCLS 19
#define HW   (768 * 768)          // 589824
#define NPIX (8 * HW)             // 4718592
#define NGRP (NPIX / 4)           // 1179648 groups of 4 pixels
#define MINKEPT 131072u
#define NBINS 8192
#define BLOCK 256
#define GRID_MAIN (NPIX / 1024)   // 4608 psum entries (layout/order preserved)

// k_main geometry: each block sweeps SEG consecutive 1024-px segments
// sequentially (loop NOT unrolled) -> same VGPR/occupancy as the best R2
// version, but each class-stream advances through 12KB contiguous runs.
#define SEG   3                   // segments (1024 px) per block, sequential
#define PXB   (SEG * 1024)        // 3072 pixels per block
#define GRID_K1 (NPIX / PXB)      // 1536 blocks = exactly 6 per CU (balanced)
#define BPI   (HW / PXB)          // 192 blocks per image (exact)

// workspace layout (bytes) — all write-before-read, no memset required
#define OFF_PSUM  ((size_t)0)                          // GRID_MAIN f32 partial sums
#define OFF_PCS   ((size_t)GRID_MAIN * 4)              // GRID_MAIN u32 sel-cnt
#define OFF_PCV   ((size_t)GRID_MAIN * 8)              // GRID_MAIN u32 valid-cnt
#define OFF_PROB  ((size_t)GRID_MAIN * 12)             // NPIX u32  (fallback only)
#define OFF_LOSS  (OFF_PROB + (size_t)NPIX * 4)        // NPIX f32  (fallback only)

typedef float    f4 __attribute__((ext_vector_type(4)));
typedef int      i4 __attribute__((ext_vector_type(4)));
typedef unsigned u4 __attribute__((ext_vector_type(4)));

struct Grp { u4 pb; f4 lo; float ls; unsigned sc; unsigned vc; };

// Pure per-group function (4 px) — per-pixel math is bit-identical to
// k_main's loop (same c-order adds). Used by k_main and the exact fallback.
__device__ __forceinline__ Grp compute4(const float* __restrict__ predict,
                                        const int* __restrict__ target,
                                        const float* __restrict__ wsh, int g)
{
    int n = g / HW;
    int p = g - n * HW;
    const float* base = predict + (size_t)n * ((size_t)NCLS * HW) + p;

    i4 t4 = __builtin_nontemporal_load((const i4*)(target + g));
    int tcx = (t4.x == -1) ? 0 : t4.x;
    int tcy = (t4.y == -1) ? 0 : t4.y;
    int tcz = (t4.z == -1) ? 0 : t4.z;
    int tcw = (t4.w == -1) ? 0 : t4.w;

    f4 s  = {0.f, 0.f, 0.f, 0.f};
    f4 vt = {0.f, 0.f, 0.f, 0.f};
#pragma unroll
    for (int c = 0; c < NCLS; ++c) {
        f4 v = __builtin_nontemporal_load((const f4*)(base + (size_t)c * HW));
        s.x += __expf(v.x); s.y += __expf(v.y);
        s.z += __expf(v.z); s.w += __expf(v.w);
        vt.x = (c == tcx) ? v.x : vt.x;
        vt.y = (c == tcy) ? v.y : vt.y;
        vt.z = (c == tcz) ? v.z : vt.z;
        vt.w = (c == tcw) ? v.w : vt.w;
    }

    bool vx = (t4.x != -1), vy = (t4.y != -1), vz = (t4.z != -1), vw = (t4.w != -1);
    float lpx = vt.x - __logf(s.x), lpy = vt.y - __logf(s.y);
    float lpz = vt.z - __logf(s.z), lpw = vt.w - __logf(s.w);
    float px = __expf(lpx), py = __expf(lpy), pz = __expf(lpz), pw = __expf(lpw);

    Grp r;
    r.pb.x = vx ? __float_as_uint(px) : 0x7F800000u;
    r.pb.y = vy ? __float_as_uint(py) : 0x7F800000u;
    r.pb.z = vz ? __float_as_uint(pz) : 0x7F800000u;
    r.pb.w = vw ? __float_as_uint(pw) : 0x7F800000u;
    r.lo.x = vx ? (-wsh[tcx] * lpx) : 0.f;
    r.lo.y = vy ? (-wsh[tcy] * lpy) : 0.f;
    r.lo.z = vz ? (-wsh[tcz] * lpz) : 0.f;
    r.lo.w = vw ? (-wsh[tcw] * lpw) : 0.f;
    bool sx = vx && (px < 0.9f), sy = vy && (py < 0.9f);
    bool sz = vz && (pz < 0.9f), sw = vw && (pw < 0.9f);
    r.ls = (sx ? r.lo.x : 0.f) + (sy ? r.lo.y : 0.f) +
           (sz ? r.lo.z : 0.f) + (sw ? r.lo.w : 0.f);
    r.sc = (unsigned)sx + (unsigned)sy + (unsigned)sz + (unsigned)sw;
    r.vc = (unsigned)vx + (unsigned)vy + (unsigned)vz + (unsigned)vw;
    return r;
}

// ---------------------------------------------------------------------------
// K1: streaming pass. Each block processes SEG=3 consecutive 1024-px
// segments SEQUENTIALLY (#pragma unroll 1): per segment the live state is
// exactly one 19-load burst + accumulators — identical registers/occupancy
// to the best (452us) 1-segment version — but each of the block's 19
// class-streams now sweeps a 12KB contiguous run, tripling DRAM-row dwell
// and halving chip-wide concurrent stream count. Grid 1536 = 6 blocks/CU
// exactly (balanced tail).
// psum layout/tree identical to the 4608-block original: segment s=bid*3+u
// covers pixels [s*1024,(s+1)*1024) with the same lane mapping and the same
// shuffle tree -> bit-identical partials.
__global__ __launch_bounds__(BLOCK) void k_main(
    const float* __restrict__ predict, const int* __restrict__ target,
    const float* __restrict__ weight, float* __restrict__ psum,
    unsigned* __restrict__ pcs, unsigned* __restrict__ pcv)
{
    __shared__ float wsh[32];
    __shared__ float red_f[4];
    __shared__ unsigned red_a[4], red_b[4];
    int tid = threadIdx.x, bid = blockIdx.x;
    if (tid < NCLS) wsh[tid] = weight[tid];
    __syncthreads();

#pragma unroll 1
    for (int u = 0; u < SEG; ++u) {
        int g = (bid * SEG + u) * 1024 + tid * 4;   // same pixel<->lane map
        Grp r = compute4(predict, target, wsh, g);

        float lsum = r.ls; unsigned scnt = r.sc, vcnt = r.vc;
#pragma unroll
        for (int d = 32; d > 0; d >>= 1) {
            lsum += __shfl_down(lsum, d);
            scnt += __shfl_down(scnt, d);
            vcnt += __shfl_down(vcnt, d);
        }
        if ((tid & 63) == 0) { red_f[tid >> 6] = lsum; red_a[tid >> 6] = scnt; red_b[tid >> 6] = vcnt; }
        __syncthreads();
        if (tid == 0) {
            psum[bid * SEG + u] = red_f[0] + red_f[1] + red_f[2] + red_f[3];
            pcs[bid * SEG + u]  = red_a[0] + red_a[1] + red_a[2] + red_a[3];
            pcv[bid * SEG + u]  = red_b[0] + red_b[1] + red_b[2] + red_b[3];
        }
        __syncthreads();
    }
}

// ---------------------------------------------------------------------------
// K2: reduce partials; decide path; write output on the common path.
// Rare path (k-th order stat >= 0.9): this SINGLE block performs the entire
// exact OHEM computation sequentially (materialize, 3-level radix select in
// LDS, select-reduce). Slow (ms) but never taken on the common path.
__global__ __launch_bounds__(BLOCK) void k_decide_fb(
    const float* __restrict__ predict, const int* __restrict__ target,
    const float* __restrict__ weight,
    const float* __restrict__ psum, const unsigned* __restrict__ pcs,
    const unsigned* __restrict__ pcv,
    unsigned* __restrict__ probbits, float* __restrict__ lossbuf,
    float* __restrict__ out)
{
    __shared__ double red_d[4];
    __shared__ unsigned red_a[4], red_b[4];
    __shared__ unsigned sh_common, sh_k;
    __shared__ float wsh[32];
    __shared__ unsigned h[NBINS];
    __shared__ unsigned wtot[4], wpre[4];
    __shared__ unsigned sel_bin, sel_rem;

    int tid = threadIdx.x;
    int lane = tid & 63, wid = tid >> 6;

    // ---- decide (common-path arithmetic identical to previous rounds) ----
    double ds = 0.0; unsigned cs = 0, cv = 0;
    for (int i = tid; i < GRID_MAIN; i += BLOCK) {
        ds += (double)psum[i]; cs += pcs[i]; cv += pcv[i];
    }
#pragma unroll
    for (int d = 32; d > 0; d >>= 1) {
        ds += __shfl_down(ds, d); cs += __shfl_down(cs, d); cv += __shfl_down(cv, d);
    }
    if (lane == 0) { red_d[wid] = ds; red_a[wid] = cs; red_b[wid] = cv; }
    __syncthreads();
    if (tid == 0) {
        double sum = red_d[0] + red_d[1] + red_d[2] + red_d[3];
        unsigned cb = red_a[0] + red_a[1] + red_a[2] + red_a[3];
        unsigned nv = red_b[0] + red_b[1] + red_b[2] + red_b[3];
        unsigned km = nv - 1u;
        unsigned k  = (MINKEPT < km) ? MINKEPT : km;
        bool common = cb > k;          // k-th order stat < 0.9 => threshold == 0.9
        sh_common = common ? 1u : 0u;
        sh_k = k;
        if (common) out[0] = (float)(sum / (double)cb);
    }
    __syncthreads();
    if (sh_common) return;             // block-uniform exit

    // =====================================================================
    // Exact fallback — single block, sequential phases.
    // =====================================================================
    unsigned k = sh_k;
    if (tid < NCLS) wsh[tid] = weight[tid];
    __syncthreads();

    // Phase A: materialize probbits + lossbuf (bit-identical recompute).
    for (int idx = tid; idx < NGRP; idx += BLOCK) {
        int g = idx * 4;
        Grp r = compute4(predict, target, wsh, g);
        *(u4*)(probbits + g) = r.pb;
        *(f4*)(lossbuf + g)  = r.lo;
    }
    __syncthreads();

    // Phase B: 3-level radix select for the exact k-th smallest prob bits.
    unsigned pref = 0, krem = k, tb = 0;
    for (int level = 0; level < 3; ++level) {
        for (int i = tid; i < NBINS; i += BLOCK) h[i] = 0;
        __syncthreads();
        for (int i = tid; i < NPIX; i += BLOCK) {
            unsigned pb = probbits[i];
            if (level == 0) atomicAdd(&h[pb >> 19], 1u);
            else if (level == 1) { if ((pb >> 19) == pref) atomicAdd(&h[(pb >> 6) & (NBINS - 1)], 1u); }
            else                 { if ((pb >> 6)  == pref) atomicAdd(&h[pb & 63u], 1u); }
        }
        __syncthreads();

        // scan of 8192 bins: 256 threads x 32 bins each
        unsigned vals[32];
        unsigned s = 0;
#pragma unroll
        for (int j = 0; j < 32; ++j) { vals[j] = h[tid * 32 + j]; s += vals[j]; }
        unsigned x = s;
        for (int d = 1; d < 64; d <<= 1) {
            unsigned y = __shfl_up(x, d);
            if (lane >= d) x += y;
        }
        if (lane == 63) wtot[wid] = x;
        __syncthreads();
        if (tid == 0) {
            unsigned a = 0;
            for (int i = 0; i < 4; ++i) { wpre[i] = a; a += wtot[i]; }
        }
        __syncthreads();
        unsigned excl = x + wpre[wid] - s;

        if (s > 0 && krem >= excl && krem < excl + s) {   // exactly one thread
            unsigned rem = krem - excl;
            unsigned cum = 0, kn = 0; int bsel = 0; bool found = false;
#pragma unroll
            for (int j = 0; j < 32; ++j) {
                if (!found && rem < cum + vals[j]) { bsel = j; kn = rem - cum; found = true; }
                cum += vals[j];
            }
            sel_bin = (unsigned)(tid * 32 + bsel);
            sel_rem = kn;
        }
        __syncthreads();
        if (level == 0)      { pref = sel_bin;                krem = sel_rem; }
        else if (level == 1) { pref = (pref << 13) | sel_bin; krem = sel_rem; }
        else                 { tb = (pref << 6) | sel_bin; }
        __syncthreads();   // protect h/sel_* before next level's reuse
    }

    // Phase C: threshold = max(kth order stat, 0.9); select-reduce; write.
    unsigned tbits = __float_as_uint(fmaxf(__uint_as_float(tb), 0.9f));
    double sacc = 0.0; unsigned c = 0;
    for (int i = tid; i < NPIX; i += BLOCK) {
        unsigned pb = probbits[i];
        if (pb < tbits) { sacc += (double)lossbuf[i]; c++; }   // uint cmp == float cmp for +floats
    }
#pragma unroll
    for (int d = 32; d > 0; d >>= 1) { sacc += __shfl_down(sacc, d); c += __shfl_down(c, d); }
    if (lane == 0) { red_d[wid] = sacc; red_a[wid] = c; }
    __syncthreads();
    if (tid == 0) {
        double dt = red_d[0] + red_d[1] + red_d[2] + red_d[3];
        unsigned cc = red_a[0] + red_a[1] + red_a[2] + red_a[3];
        out[0] = (float)(dt / (double)cc);
    }
}

// ---------------------------------------------------------------------------
extern "C" void kernel_launch(void* const* d_in, const int* in_sizes, int n_in,
                              void* d_out, int out_size, void* d_ws, size_t ws_size,
                              hipStream_t stream)
{
    const float* predict = (const float*)d_in[0];
    const int*   target  = (const int*)d_in[1];
    const float* weight  = (const float*)d_in[2];
    char* ws = (char*)d_ws;
    float* out = (float*)d_out;

    float*    psum     = (float*)(ws + OFF_PSUM);
    unsigned* pcs      = (unsigned*)(ws + OFF_PCS);
    unsigned* pcv      = (unsigned*)(ws + OFF_PCV);
    unsigned* probbits = (unsigned*)(ws + OFF_PROB);
    float*    lossbuf  = (float*)(ws + OFF_LOSS);

    k_main<<<GRID_K1, BLOCK, 0, stream>>>(predict, target, weight, psum, pcs, pcv);
    k_decide_fb<<<1, BLOCK, 0, stream>>>(predict, target, weight,
                                         psum, pcs, pcv, probbits, lossbuf, out);
}

// Round 6
// 452.299 us; speedup vs baseline: 1.1379x; 1.0045x over previous
//
#include <hip/hip_runtime.h>
#include <stdint.h>

#define NCLS 19
#define HW   (768 * 768)          // 589824
#define NPIX (8 * HW)             // 4718592
#define NGRP (NPIX / 4)           // 1179648 groups of 4 pixels
#define MINKEPT 131072u
#define NBINS 8192
#define BLOCK 256
#define GRID_MAIN (NPIX / 1024)   // 4608 psum entries (layout/order preserved)
#define GRID_K1 GRID_MAIN         // one 1024-px segment per block (R2 mapping)

// workspace layout (bytes) — all write-before-read, no memset required
#define OFF_PSUM  ((size_t)0)                          // GRID_MAIN f32 partial sums
#define OFF_PCS   ((size_t)GRID_MAIN * 4)              // GRID_MAIN u32 sel-cnt
#define OFF_PCV   ((size_t)GRID_MAIN * 8)              // GRID_MAIN u32 valid-cnt
#define OFF_PROB  ((size_t)GRID_MAIN * 12)             // NPIX u32  (fallback only)
#define OFF_LOSS  (OFF_PROB + (size_t)NPIX * 4)        // NPIX f32  (fallback only)

typedef float    f4 __attribute__((ext_vector_type(4)));
typedef int      i4 __attribute__((ext_vector_type(4)));
typedef unsigned u4 __attribute__((ext_vector_type(4)));

struct Grp { u4 pb; f4 lo; float ls; unsigned sc; unsigned vc; };

// Pure per-group function (4 px) — exact fallback only. Same c=0..18 add
// order as k_main's batched loop -> identical math.
__device__ __forceinline__ Grp compute4(const float* __restrict__ predict,
                                        const int* __restrict__ target,
                                        const float* __restrict__ wsh, int g)
{
    int n = g / HW;
    int p = g - n * HW;
    const float* base = predict + (size_t)n * ((size_t)NCLS * HW) + p;

    i4 t4 = __builtin_nontemporal_load((const i4*)(target + g));
    int tcx = (t4.x == -1) ? 0 : t4.x;
    int tcy = (t4.y == -1) ? 0 : t4.y;
    int tcz = (t4.z == -1) ? 0 : t4.z;
    int tcw = (t4.w == -1) ? 0 : t4.w;

    f4 s  = {0.f, 0.f, 0.f, 0.f};
    f4 vt = {0.f, 0.f, 0.f, 0.f};
#pragma unroll
    for (int c = 0; c < NCLS; ++c) {
        f4 v = __builtin_nontemporal_load((const f4*)(base + (size_t)c * HW));
        s.x += __expf(v.x); s.y += __expf(v.y);
        s.z += __expf(v.z); s.w += __expf(v.w);
        vt.x = (c == tcx) ? v.x : vt.x;
        vt.y = (c == tcy) ? v.y : vt.y;
        vt.z = (c == tcz) ? v.z : vt.z;
        vt.w = (c == tcw) ? v.w : vt.w;
    }

    bool vx = (t4.x != -1), vy = (t4.y != -1), vz = (t4.z != -1), vw = (t4.w != -1);
    float lpx = vt.x - __logf(s.x), lpy = vt.y - __logf(s.y);
    float lpz = vt.z - __logf(s.z), lpw = vt.w - __logf(s.w);
    float px = __expf(lpx), py = __expf(lpy), pz = __expf(lpz), pw = __expf(lpw);

    Grp r;
    r.pb.x = vx ? __float_as_uint(px) : 0x7F800000u;
    r.pb.y = vy ? __float_as_uint(py) : 0x7F800000u;
    r.pb.z = vz ? __float_as_uint(pz) : 0x7F800000u;
    r.pb.w = vw ? __float_as_uint(pw) : 0x7F800000u;
    r.lo.x = vx ? (-wsh[tcx] * lpx) : 0.f;
    r.lo.y = vy ? (-wsh[tcy] * lpy) : 0.f;
    r.lo.z = vz ? (-wsh[tcz] * lpz) : 0.f;
    r.lo.w = vw ? (-wsh[tcw] * lpw) : 0.f;
    bool sx = vx && (px < 0.9f), sy = vy && (py < 0.9f);
    bool sz = vz && (pz < 0.9f), sw = vw && (pw < 0.9f);
    r.ls = (sx ? r.lo.x : 0.f) + (sy ? r.lo.y : 0.f) +
           (sz ? r.lo.z : 0.f) + (sw ? r.lo.w : 0.f);
    r.sc = (unsigned)sx + (unsigned)sy + (unsigned)sz + (unsigned)sw;
    r.vc = (unsigned)vx + (unsigned)vy + (unsigned)vz + (unsigned)vw;
    return r;
}

// ---------------------------------------------------------------------------
// K1: streaming pass, R2 pixel mapping (one 1024-px segment per block), but
// the 19-class sweep is batched 5+5+5+4 with a #pragma unroll 1 batch loop
// and __launch_bounds__(256,8): live set ~50 VGPR -> 64-VGPR cap holds ->
// 8 waves/SIMD (2x the 4-waves/SIMD of the 19-live-loads version). Probes
// the occupancy axis of the read path: writes (the 6.5TB/s fill) need no
// latency hiding at 10% occupancy; reads do. Accumulation order c=0..18,
// finalize, shuffle tree, psum layout all unchanged -> bit-identical.
__global__ __launch_bounds__(BLOCK, 8) void k_main(
    const float* __restrict__ predict, const int* __restrict__ target,
    const float* __restrict__ weight, float* __restrict__ psum,
    unsigned* __restrict__ pcs, unsigned* __restrict__ pcv)
{
    __shared__ float wsh[32];
    __shared__ float red_f[4];
    __shared__ unsigned red_a[4], red_b[4];
    int tid = threadIdx.x, bid = blockIdx.x;
    if (tid < NCLS) wsh[tid] = weight[tid];
    __syncthreads();

    int g = bid * 1024 + tid * 4;          // same pixel<->lane map as R2
    int n = g / HW;
    int p = g - n * HW;
    const float* base = predict + (size_t)n * ((size_t)NCLS * HW) + p;

    i4 t4 = __builtin_nontemporal_load((const i4*)(target + g));
    int tcx = (t4.x == -1) ? 0 : t4.x;
    int tcy = (t4.y == -1) ? 0 : t4.y;
    int tcz = (t4.z == -1) ? 0 : t4.z;
    int tcw = (t4.w == -1) ? 0 : t4.w;

    f4 s  = {0.f, 0.f, 0.f, 0.f};
    f4 vt = {0.f, 0.f, 0.f, 0.f};

    // batches of 5 classes: 0-4, 5-9, 10-14 (runtime c0 -> small live set)
#pragma unroll 1
    for (int c0 = 0; c0 < 15; c0 += 5) {
        f4 v[5];
#pragma unroll
        for (int j = 0; j < 5; ++j)
            v[j] = __builtin_nontemporal_load(
                (const f4*)(base + (size_t)(c0 + j) * HW));
#pragma unroll
        for (int j = 0; j < 5; ++j) {
            int c = c0 + j;
            s.x += __expf(v[j].x); s.y += __expf(v[j].y);
            s.z += __expf(v[j].z); s.w += __expf(v[j].w);
            vt.x = (c == tcx) ? v[j].x : vt.x;
            vt.y = (c == tcy) ? v[j].y : vt.y;
            vt.z = (c == tcz) ? v[j].z : vt.z;
            vt.w = (c == tcw) ? v[j].w : vt.w;
        }
    }
    // tail batch: classes 15..18
    {
        f4 v[4];
#pragma unroll
        for (int j = 0; j < 4; ++j)
            v[j] = __builtin_nontemporal_load(
                (const f4*)(base + (size_t)(15 + j) * HW));
#pragma unroll
        for (int j = 0; j < 4; ++j) {
            int c = 15 + j;
            s.x += __expf(v[j].x); s.y += __expf(v[j].y);
            s.z += __expf(v[j].z); s.w += __expf(v[j].w);
            vt.x = (c == tcx) ? v[j].x : vt.x;
            vt.y = (c == tcy) ? v[j].y : vt.y;
            vt.z = (c == tcz) ? v[j].z : vt.z;
            vt.w = (c == tcw) ? v[j].w : vt.w;
        }
    }

    // finalize — identical expression tree to compute4
    bool vx = (t4.x != -1), vy = (t4.y != -1), vz = (t4.z != -1), vw = (t4.w != -1);
    float lpx = vt.x - __logf(s.x), lpy = vt.y - __logf(s.y);
    float lpz = vt.z - __logf(s.z), lpw = vt.w - __logf(s.w);
    float px = __expf(lpx), py = __expf(lpy), pz = __expf(lpz), pw = __expf(lpw);
    float lox  = vx ? (-wsh[tcx] * lpx) : 0.f;
    float loy  = vy ? (-wsh[tcy] * lpy) : 0.f;
    float loz  = vz ? (-wsh[tcz] * lpz) : 0.f;
    float low_ = vw ? (-wsh[tcw] * lpw) : 0.f;
    bool sx = vx && (px < 0.9f), sy = vy && (py < 0.9f);
    bool sz = vz && (pz < 0.9f), sw = vw && (pw < 0.9f);
    float lsum = (sx ? lox : 0.f) + (sy ? loy : 0.f) +
                 (sz ? loz : 0.f) + (sw ? low_ : 0.f);
    unsigned scnt = (unsigned)sx + (unsigned)sy + (unsigned)sz + (unsigned)sw;
    unsigned vcnt = (unsigned)vx + (unsigned)vy + (unsigned)vz + (unsigned)vw;

#pragma unroll
    for (int d = 32; d > 0; d >>= 1) {
        lsum += __shfl_down(lsum, d);
        scnt += __shfl_down(scnt, d);
        vcnt += __shfl_down(vcnt, d);
    }
    if ((tid & 63) == 0) { red_f[tid >> 6] = lsum; red_a[tid >> 6] = scnt; red_b[tid >> 6] = vcnt; }
    __syncthreads();
    if (tid == 0) {
        psum[bid] = red_f[0] + red_f[1] + red_f[2] + red_f[3];
        pcs[bid]  = red_a[0] + red_a[1] + red_a[2] + red_a[3];
        pcv[bid]  = red_b[0] + red_b[1] + red_b[2] + red_b[3];
    }
}

// ---------------------------------------------------------------------------
// K2: reduce partials; decide path; write output on the common path.
// Rare path (k-th order stat >= 0.9): this SINGLE block performs the entire
// exact OHEM computation sequentially (materialize, 3-level radix select in
// LDS, select-reduce). Slow (ms) but never taken on the common path.
__global__ __launch_bounds__(BLOCK) void k_decide_fb(
    const float* __restrict__ predict, const int* __restrict__ target,
    const float* __restrict__ weight,
    const float* __restrict__ psum, const unsigned* __restrict__ pcs,
    const unsigned* __restrict__ pcv,
    unsigned* __restrict__ probbits, float* __restrict__ lossbuf,
    float* __restrict__ out)
{
    __shared__ double red_d[4];
    __shared__ unsigned red_a[4], red_b[4];
    __shared__ unsigned sh_common, sh_k;
    __shared__ float wsh[32];
    __shared__ unsigned h[NBINS];
    __shared__ unsigned wtot[4], wpre[4];
    __shared__ unsigned sel_bin, sel_rem;

    int tid = threadIdx.x;
    int lane = tid & 63, wid = tid >> 6;

    // ---- decide (common-path arithmetic identical to previous rounds) ----
    double ds = 0.0; unsigned cs = 0, cv = 0;
    for (int i = tid; i < GRID_MAIN; i += BLOCK) {
        ds += (double)psum[i]; cs += pcs[i]; cv += pcv[i];
    }
#pragma unroll
    for (int d = 32; d > 0; d >>= 1) {
        ds += __shfl_down(ds, d); cs += __shfl_down(cs, d); cv += __shfl_down(cv, d);
    }
    if (lane == 0) { red_d[wid] = ds; red_a[wid] = cs; red_b[wid] = cv; }
    __syncthreads();
    if (tid == 0) {
        double sum = red_d[0] + red_d[1] + red_d[2] + red_d[3];
        unsigned cb = red_a[0] + red_a[1] + red_a[2] + red_a[3];
        unsigned nv = red_b[0] + red_b[1] + red_b[2] + red_b[3];
        unsigned km = nv - 1u;
        unsigned k  = (MINKEPT < km) ? MINKEPT : km;
        bool common = cb > k;          // k-th order stat < 0.9 => threshold == 0.9
        sh_common = common ? 1u : 0u;
        sh_k = k;
        if (common) out[0] = (float)(sum / (double)cb);
    }
    __syncthreads();
    if (sh_common) return;             // block-uniform exit

    // =====================================================================
    // Exact fallback — single block, sequential phases.
    // =====================================================================
    unsigned k = sh_k;
    if (tid < NCLS) wsh[tid] = weight[tid];
    __syncthreads();

    // Phase A: materialize probbits + lossbuf.
    for (int idx = tid; idx < NGRP; idx += BLOCK) {
        int g = idx * 4;
        Grp r = compute4(predict, target, wsh, g);
        *(u4*)(probbits + g) = r.pb;
        *(f4*)(lossbuf + g)  = r.lo;
    }
    __syncthreads();

    // Phase B: 3-level radix select for the exact k-th smallest prob bits.
    unsigned pref = 0, krem = k, tb = 0;
    for (int level = 0; level < 3; ++level) {
        for (int i = tid; i < NBINS; i += BLOCK) h[i] = 0;
        __syncthreads();
        for (int i = tid; i < NPIX; i += BLOCK) {
            unsigned pb = probbits[i];
            if (level == 0) atomicAdd(&h[pb >> 19], 1u);
            else if (level == 1) { if ((pb >> 19) == pref) atomicAdd(&h[(pb >> 6) & (NBINS - 1)], 1u); }
            else                 { if ((pb >> 6)  == pref) atomicAdd(&h[pb & 63u], 1u); }
        }
        __syncthreads();

        // scan of 8192 bins: 256 threads x 32 bins each
        unsigned vals[32];
        unsigned s = 0;
#pragma unroll
        for (int j = 0; j < 32; ++j) { vals[j] = h[tid * 32 + j]; s += vals[j]; }
        unsigned x = s;
        for (int d = 1; d < 64; d <<= 1) {
            unsigned y = __shfl_up(x, d);
            if (lane >= d) x += y;
        }
        if (lane == 63) wtot[wid] = x;
        __syncthreads();
        if (tid == 0) {
            unsigned a = 0;
            for (int i = 0; i < 4; ++i) { wpre[i] = a; a += wtot[i]; }
        }
        __syncthreads();
        unsigned excl = x + wpre[wid] - s;

        if (s > 0 && krem >= excl && krem < excl + s) {   // exactly one thread
            unsigned rem = krem - excl;
            unsigned cum = 0, kn = 0; int bsel = 0; bool found = false;
#pragma unroll
            for (int j = 0; j < 32; ++j) {
                if (!found && rem < cum + vals[j]) { bsel = j; kn = rem - cum; found = true; }
                cum += vals[j];
            }
            sel_bin = (unsigned)(tid * 32 + bsel);
            sel_rem = kn;
        }
        __syncthreads();
        if (level == 0)      { pref = sel_bin;                krem = sel_rem; }
        else if (level == 1) { pref = (pref << 13) | sel_bin; krem = sel_rem; }
        else                 { tb = (pref << 6) | sel_bin; }
        __syncthreads();   // protect h/sel_* before next level's reuse
    }

    // Phase C: threshold = max(kth order stat, 0.9); select-reduce; write.
    unsigned tbits = __float_as_uint(fmaxf(__uint_as_float(tb), 0.9f));
    double sacc = 0.0; unsigned c = 0;
    for (int i = tid; i < NPIX; i += BLOCK) {
        unsigned pb = probbits[i];
        if (pb < tbits) { sacc += (double)lossbuf[i]; c++; }   // uint cmp == float cmp for +floats
    }
#pragma unroll
    for (int d = 32; d > 0; d >>= 1) { sacc += __shfl_down(sacc, d); c += __shfl_down(c, d); }
    if (lane == 0) { red_d[wid] = sacc; red_a[wid] = c; }
    __syncthreads();
    if (tid == 0) {
        double dt = red_d[0] + red_d[1] + red_d[2] + red_d[3];
        unsigned cc = red_a[0] + red_a[1] + red_a[2] + red_a[3];
        out[0] = (float)(dt / (double)cc);
    }
}

// ---------------------------------------------------------------------------
extern "C" void kernel_launch(void* const* d_in, const int* in_sizes, int n_in,
                              void* d_out, int out_size, void* d_ws, size_t ws_size,
                              hipStream_t stream)
{
    const float* predict = (const float*)d_in[0];
    const int*   target  = (const int*)d_in[1];
    const float* weight  = (const float*)d_in[2];
    char* ws = (char*)d_ws;
    float* out = (float*)d_out;

    float*    psum     = (float*)(ws + OFF_PSUM);
    unsigned* pcs      = (unsigned*)(ws + OFF_PCS);
    unsigned* pcv      = (unsigned*)(ws + OFF_PCV);
    unsigned* probbits = (unsigned*)(ws + OFF_PROB);
    float*    lossbuf  = (float*)(ws + OFF_LOSS);

    k_main<<<GRID_K1, BLOCK, 0, stream>>>(predict, target, weight, psum, pcs, pcv);
    k_decide_fb<<<1, BLOCK, 0, stream>>>(predict, target, weight,
                                         psum, pcs, pcv, probbits, lossbuf, out);
}